// Round 6
// baseline (271.621 us; speedup 1.0000x reference)
//
#include <hip/hip_runtime.h>
#include <hip/hip_bf16.h>

#define BN   2
#define SEQ  2048
#define DIM  1024
#define NH   16
#define HD   64
#define D4   4096
#define MAXS 4096

using bf16 = __hip_bfloat16;
typedef __bf16 bf16x8 __attribute__((ext_vector_type(8)));
typedef float  f32x4  __attribute__((ext_vector_type(4)));

__device__ __forceinline__ float bf2f(bf16 v){ return __bfloat162float(v); }
__device__ __forceinline__ bf16  f2bf(float v){ return __float2bfloat16(v); }
__device__ __forceinline__ float silu_f(float v){
  const float e = __expf(-v);
  return v * __builtin_amdgcn_rcpf(1.f + e);
}

__device__ __forceinline__ void async16(void* lds, const void* g){
  __builtin_amdgcn_global_load_lds((const __attribute__((address_space(1))) void*)g,
                                   (__attribute__((address_space(3))) void*)lds, 16, 0, 0);
}
__device__ __forceinline__ f32x4 mfma16(bf16x8 a, bf16x8 b, f32x4 c){
  return __builtin_amdgcn_mfma_f32_16x16x32_bf16(a, b, c, 0, 0, 0);
}

// ---------------- fp32 -> bf16 convert (3 arrays, 1 launch) ----------------
__global__ __launch_bounds__(256) void f2bk3(
    const float* __restrict__ a, bf16* __restrict__ ao, int na,
    const float* __restrict__ b, bf16* __restrict__ bo, int nb,
    const float* __restrict__ c, bf16* __restrict__ co)
{
  int i = (blockIdx.x * 256 + threadIdx.x) * 4;
  const float* in; bf16* out;
  if (i < na){ in = a; out = ao; }
  else if (i < na + nb){ in = b; out = bo; i -= na; }
  else { in = c; out = co; i -= na + nb; }
  const float4 v = *(const float4*)(in + i);
  bf16 t0 = f2bf(v.x), t1 = f2bf(v.y), t2 = f2bf(v.z), t3 = f2bf(v.w);
  ushort4 o;
  o.x = *(unsigned short*)&t0; o.y = *(unsigned short*)&t1;
  o.z = *(unsigned short*)&t2; o.w = *(unsigned short*)&t3;
  *(ushort4*)((unsigned short*)out + i) = o;
}

// ---------------- GEMM1: C = silu(A @ W^T + bias); v-tiles write transposed vt ----------------
template<int NTOT>
__global__ __launch_bounds__(256) void gemm_bt(
    const bf16* __restrict__ A, const bf16* __restrict__ W,
    const float* __restrict__ bias, bf16* __restrict__ outb, bf16* __restrict__ vt)
{
  constexpr int K = DIM;
  const int ntiles = NTOT / 128;
  const int m0 = (int)(blockIdx.x / ntiles) * 128;
  const int n0 = (int)(blockIdx.x % ntiles) * 128;
  __shared__ bf16 Al[128*32];
  __shared__ bf16 Bl[128*32];
  const int tid = threadIdx.x, wave = tid>>6, lane = tid&63;
  const int quad = lane>>4, l16 = lane&15;
  const int srow = lane>>2;
  const int sg   = ((lane&3) ^ ((lane>>3)&3)) * 8;
  const int wm = (wave>>1)*64, wn = (wave&1)*64;
  const int rkey = ((l16>>1)&3);

  f32x4 acc[4][4];
  #pragma unroll
  for (int i=0;i<4;i++)
    #pragma unroll
    for (int j=0;j<4;j++) acc[i][j] = (f32x4){0.f,0.f,0.f,0.f};

  const bf16* aB = A + m0*K;
  const bf16* wB = W + n0*K;

  for (int k0 = 0; k0 < K; k0 += 32){
    async16(&Al[wave*1024      ], aB + (wave*32      + srow)*K + k0 + sg);
    async16(&Al[wave*1024 + 512], aB + (wave*32 + 16 + srow)*K + k0 + sg);
    async16(&Bl[wave*1024      ], wB + (wave*32      + srow)*K + k0 + sg);
    async16(&Bl[wave*1024 + 512], wB + (wave*32 + 16 + srow)*K + k0 + sg);
    __syncthreads();
    bf16x8 af[4], bv[4];
    #pragma unroll
    for (int mt=0;mt<4;mt++) af[mt] = *(const bf16x8*)&Al[(wm+mt*16+l16)*32 + (quad ^ rkey)*8];
    #pragma unroll
    for (int nt=0;nt<4;nt++) bv[nt] = *(const bf16x8*)&Bl[(wn+nt*16+l16)*32 + (quad ^ rkey)*8];
    #pragma unroll
    for (int mt=0;mt<4;mt++)
      #pragma unroll
      for (int nt=0;nt<4;nt++)
        acc[mt][nt] = mfma16(af[mt], bv[nt], acc[mt][nt]);
    __syncthreads();
  }

  const bool vtile = (NTOT == 4096) && (n0 >= 3*DIM);
  if (!vtile){
    #pragma unroll
    for (int mt=0;mt<4;mt++){
      #pragma unroll
      for (int nt=0;nt<4;nt++){
        const int row = m0 + wm + mt*16 + quad*4;
        const int col = n0 + wn + nt*16 + l16;
        const float bvv = bias[col];
        #pragma unroll
        for (int r=0;r<4;r++){
          float v = silu_f(acc[mt][nt][r] + bvv);
          outb[(row+r)*NTOT + col] = f2bf(v);
        }
      }
    }
  } else {
    // v slice: write transposed directly to vt[b][hh][d][s] (4 consecutive s -> 8B store)
    #pragma unroll
    for (int mt=0;mt<4;mt++){
      #pragma unroll
      for (int nt=0;nt<4;nt++){
        const int row = m0 + wm + mt*16 + quad*4;
        const int colg = n0 + wn + nt*16 + l16;
        const float bvv = bias[colg];
        const int col = colg - 3*DIM;
        const int hh = col >> 6, d = col & 63;
        const int bb = row >> 11, sl = row & 2047;
        ushort4 o;
        float v0 = silu_f(acc[mt][nt][0] + bvv);
        float v1 = silu_f(acc[mt][nt][1] + bvv);
        float v2 = silu_f(acc[mt][nt][2] + bvv);
        float v3 = silu_f(acc[mt][nt][3] + bvv);
        bf16 t0=f2bf(v0), t1=f2bf(v1), t2=f2bf(v2), t3=f2bf(v3);
        o.x=*(unsigned short*)&t0; o.y=*(unsigned short*)&t1;
        o.z=*(unsigned short*)&t2; o.w=*(unsigned short*)&t3;
        *(ushort4*)&vt[((bb*NH + hh)*HD + d)*SEQ + sl] = o;
      }
    }
  }
}

// ---------------- GEMM2: z = A @ W^T + bias + resid, 128x64 tile, fp32 out ----------------
__global__ __launch_bounds__(256) void gemm_bt2(
    const bf16* __restrict__ A, const bf16* __restrict__ W,
    const float* __restrict__ bias, const float* __restrict__ resid,
    float* __restrict__ outf)
{
  constexpr int K = DIM, NTOT = DIM;
  const int ntiles = NTOT / 64;
  const int m0 = (int)(blockIdx.x / ntiles) * 128;
  const int n0 = (int)(blockIdx.x % ntiles) * 64;
  __shared__ bf16 Al[128*32];
  __shared__ bf16 Bl[64*32];
  const int tid = threadIdx.x, wave = tid>>6, lane = tid&63;
  const int quad = lane>>4, l16 = lane&15;
  const int srow = lane>>2;
  const int sg   = ((lane&3) ^ ((lane>>3)&3)) * 8;
  const int wm = wave*32;
  const int rkey = ((l16>>1)&3);

  f32x4 acc[2][4];
  #pragma unroll
  for (int i=0;i<2;i++)
    #pragma unroll
    for (int j=0;j<4;j++) acc[i][j] = (f32x4){0.f,0.f,0.f,0.f};

  const bf16* aB = A + m0*K;
  const bf16* wB = W + n0*K;

  for (int k0 = 0; k0 < K; k0 += 32){
    async16(&Al[wave*1024      ], aB + (wave*32      + srow)*K + k0 + sg);
    async16(&Al[wave*1024 + 512], aB + (wave*32 + 16 + srow)*K + k0 + sg);
    async16(&Bl[wave*512       ], wB + (wave*16      + srow)*K + k0 + sg);
    __syncthreads();
    bf16x8 af[2], bv[4];
    #pragma unroll
    for (int mt=0;mt<2;mt++) af[mt] = *(const bf16x8*)&Al[(wm+mt*16+l16)*32 + (quad ^ rkey)*8];
    #pragma unroll
    for (int nt=0;nt<4;nt++) bv[nt] = *(const bf16x8*)&Bl[(nt*16+l16)*32 + (quad ^ rkey)*8];
    #pragma unroll
    for (int mt=0;mt<2;mt++)
      #pragma unroll
      for (int nt=0;nt<4;nt++)
        acc[mt][nt] = mfma16(af[mt], bv[nt], acc[mt][nt]);
    __syncthreads();
  }

  #pragma unroll
  for (int mt=0;mt<2;mt++){
    #pragma unroll
    for (int nt=0;nt<4;nt++){
      const int row = m0 + wm + mt*16 + quad*4;
      const int col = n0 + nt*16 + l16;
      const float bvv = bias[col];
      #pragma unroll
      for (int r=0;r<4;r++){
        outf[(row+r)*NTOT + col] = acc[mt][nt][r] + bvv + resid[(row+r)*NTOT + col];
      }
    }
  }
}

// ---------------- attention: q-tile 128, k-chunk 64, double-buffered async pipeline ----------------
// Pairs {t, 15-t}: every block 34 uniform k-iters. bid%8 = XCD -> (b,head) L2-locality.
// Pipeline: stage(next) -> s_waitcnt vmcnt(5); s_barrier -> compute -> s_waitcnt lgkmcnt(0); s_barrier.
// Prefetch stays in flight across the barrier (never vmcnt(0) mid-loop).
__global__ __launch_bounds__(256) void attn(
    const bf16* __restrict__ h, const bf16* __restrict__ vt,
    const float* __restrict__ pw, bf16* __restrict__ y)
{
  const int bid = blockIdx.x;
  const int xcd  = bid & 7;
  const int slot = bid >> 3;          // 0..31
  const int p    = slot & 7;          // pair index 0..7
  const int g    = ((slot >> 3) << 3) | xcd;   // (b,head) group 0..31
  const int hh = g & 15, b = g >> 4;

  __shared__ bf16 Kl[2][64*64];       // [kpos][d], groups XOR-swizzled by kpos&7
  __shared__ bf16 Vl[2][64*64];       // [d][kpos], groups XOR-swizzled by d&7
  __shared__ bf16 Pl[4][32*72];       // per-wave P, stride 72
  __shared__ float pwl[2][256];

  const int tid = threadIdx.x, wave = tid>>6, lane = tid&63;
  const int quad = lane>>4, l16 = lane&15;
  const int r8 = lane>>3;
  const int g8 = ((lane&7) ^ r8)*8;   // swizzled group offset (elems) for staging

  const bf16* kgb = h + b*SEQ*D4 + 2*DIM + hh*HD;
  const bf16* vgb = vt + (b*NH + hh)*HD*SEQ;

  for (int pass = 0; pass < 2; ++pass){
    const int t = pass ? (15 - p) : p;
    const int q0 = t * 128;

    bf16x8 qf[2][2];
    #pragma unroll
    for (int mt=0;mt<2;mt++){
      const bf16* qb = h + (b*SEQ + q0 + wave*32 + mt*16 + l16)*D4 + DIM + hh*HD;
      qf[mt][0] = *(const bf16x8*)(qb + quad*8);
      qf[mt][1] = *(const bf16x8*)(qb + 32 + quad*8);
    }

    f32x4 oacc[2][4];
    #pragma unroll
    for (int mt=0;mt<2;mt++)
      #pragma unroll
      for (int nt=0;nt<4;nt++) oacc[mt][nt] = (f32x4){0.f,0.f,0.f,0.f};

    const int niter = 2*(t+1);

    // prologue: stage chunk 0 into buf 0 (5 async16 per wave)
    #pragma unroll
    for (int tt=0;tt<2;tt++)
      async16(&Kl[0][(wave*16 + tt*8)*64], kgb + (wave*16 + tt*8 + r8)*D4 + g8);
    #pragma unroll
    for (int tt=0;tt<2;tt++)
      async16(&Vl[0][(wave*16 + tt*8)*64], vgb + (wave*16 + tt*8 + r8)*SEQ + g8);
    async16(&pwl[0][0], pw + (MAXS-1 - q0 - 127) + lane*4);

    for (int it = 0; it < niter; ++it){
      const int cur = it & 1;
      const int k0 = it * 64;
      if (it + 1 < niter){
        const int nb = cur ^ 1, kn = k0 + 64;
        #pragma unroll
        for (int tt=0;tt<2;tt++)
          async16(&Kl[nb][(wave*16 + tt*8)*64], kgb + (kn + wave*16 + tt*8 + r8)*D4 + g8);
        #pragma unroll
        for (int tt=0;tt<2;tt++)
          async16(&Vl[nb][(wave*16 + tt*8)*64], vgb + (wave*16 + tt*8 + r8)*SEQ + kn + g8);
        async16(&pwl[nb][0], pw + (MAXS-1 + kn - q0 - 127) + lane*4);
        asm volatile("s_waitcnt vmcnt(5)\ns_barrier" ::: "memory");
      } else {
        asm volatile("s_waitcnt vmcnt(0)\ns_barrier" ::: "memory");
      }

      // S = Q @ K^T  (m=32 rows/wave as 2 frags, n=64, k=64)
      f32x4 sacc[2][4];
      #pragma unroll
      for (int mt=0;mt<2;mt++)
        #pragma unroll
        for (int nt=0;nt<4;nt++) sacc[mt][nt] = (f32x4){0.f,0.f,0.f,0.f};
      #pragma unroll
      for (int ks=0;ks<2;ks++){
        #pragma unroll
        for (int nt=0;nt<4;nt++){
          bf16x8 kf = *(const bf16x8*)&Kl[cur][(nt*16 + l16)*64 + ((ks*4 + quad) ^ (l16&7))*8];
          sacc[0][nt] = mfma16(qf[0][ks], kf, sacc[0][nt]);
          sacc[1][nt] = mfma16(qf[1][ks], kf, sacc[1][nt]);
        }
      }

      // bias + silu + causal -> Pl (per-wave)
      const int dq = q0 - k0;
      #pragma unroll
      for (int mt=0;mt<2;mt++){
        const int i0 = wave*32 + mt*16 + quad*4;
        #pragma unroll
        for (int nt=0;nt<4;nt++){
          const int lj = nt*16 + l16;
          #pragma unroll
          for (int r=0;r<4;r++){
            const int d = lj - (i0 + r);
            const float bias = pwl[cur][d + 127];
            const float sv = silu_f(sacc[mt][nt][r] + bias);
            Pl[wave][(mt*16 + quad*4 + r)*72 + lj] = f2bf((d <= dq) ? sv : 0.f);
          }
        }
      }

      // O += P @ V  (k=64 as 2 ks)
      #pragma unroll
      for (int ks=0;ks<2;ks++){
        bf16x8 pf0 = *(const bf16x8*)&Pl[wave][(l16     )*72 + ks*32 + quad*8];
        bf16x8 pf1 = *(const bf16x8*)&Pl[wave][(16 + l16)*72 + ks*32 + quad*8];
        #pragma unroll
        for (int nt=0;nt<4;nt++){
          bf16x8 vf = *(const bf16x8*)&Vl[cur][(nt*16 + l16)*64 + ((ks*4 + quad) ^ (l16&7))*8];
          oacc[0][nt] = mfma16(pf0, vf, oacc[0][nt]);
          oacc[1][nt] = mfma16(pf1, vf, oacc[1][nt]);
        }
      }
      asm volatile("s_waitcnt lgkmcnt(0)\ns_barrier" ::: "memory");
    }

    // epilogue: multiply by u, write y
    #pragma unroll
    for (int mt=0;mt<2;mt++){
      const int qrow = q0 + wave*32 + mt*16 + quad*4;
      #pragma unroll
      for (int nt=0;nt<4;nt++){
        const int c = hh*HD + nt*16 + l16;
        #pragma unroll
        for (int r=0;r<4;r++){
          const int srow = b*SEQ + qrow + r;
          const float uu = bf2f(h[srow*D4 + c]);
          y[srow*DIM + c] = f2bf(oacc[mt][nt][r] * uu);
        }
      }
    }
    __syncthreads();   // protect all LDS buffers before next pass prologue
  }
}

// ---------------- row layernorm over D=1024 ----------------
template<bool FP32IN, bool FP32OUT>
__global__ __launch_bounds__(256) void lnorm(const void* __restrict__ in,
    const float* __restrict__ g, const float* __restrict__ be, void* __restrict__ out)
{
  const int row = blockIdx.x;
  const int tid = threadIdx.x, wave = tid>>6, lane = tid&63;
  const int c0 = tid*4;
  float v[4];
  if (FP32IN){
    const float* p = (const float*)in + row*DIM + c0;
    #pragma unroll
    for (int j=0;j<4;j++) v[j] = p[j];
  } else {
    const bf16* p = (const bf16*)in + row*DIM + c0;
    #pragma unroll
    for (int j=0;j<4;j++) v[j] = bf2f(p[j]);
  }
  float s = 0.f, ss = 0.f;
  #pragma unroll
  for (int j=0;j<4;j++){ s += v[j]; ss += v[j]*v[j]; }
  #pragma unroll
  for (int off=32; off>0; off>>=1){
    s  += __shfl_down(s, off);
    ss += __shfl_down(ss, off);
  }
  __shared__ float red[8];
  if (lane==0){ red[wave] = s; red[4+wave] = ss; }
  __syncthreads();
  s  = red[0]+red[1]+red[2]+red[3];
  ss = red[4]+red[5]+red[6]+red[7];
  const float mu   = s * (1.f/DIM);
  const float var  = ss * (1.f/DIM) - mu*mu;
  const float rstd = rsqrtf(var + 1e-5f);
  #pragma unroll
  for (int j=0;j<4;j++){
    const int c = c0 + j;
    const float o = (v[j]-mu)*rstd*g[c] + be[c];
    if (FP32OUT) ((float*)out)[row*DIM + c] = o;
    else         ((bf16*)out)[row*DIM + c] = f2bf(o);
  }
}

extern "C" void kernel_launch(void* const* d_in, const int* in_sizes, int n_in,
                              void* d_out, int out_size, void* d_ws, size_t ws_size,
                              hipStream_t stream)
{
  const float* x   = (const float*)d_in[0];
  const float* w1  = (const float*)d_in[2];
  const float* b1  = (const float*)d_in[3];
  const float* w2  = (const float*)d_in[4];
  const float* b2  = (const float*)d_in[5];
  const float* g1  = (const float*)d_in[6];
  const float* be1 = (const float*)d_in[7];
  const float* g2  = (const float*)d_in[8];
  const float* be2 = (const float*)d_in[9];
  const float* pw  = (const float*)d_in[10];

  char* ws = (char*)d_ws;
  bf16*  h   = (bf16*)(ws);
  bf16*  vt  = (bf16*)(ws + (32u<<20));
  bf16*  y   = (bf16*)(ws + (40u<<20));
  bf16*  xb  = (bf16*)(ws + (48u<<20));
  bf16*  w1b = (bf16*)(ws + (56u<<20));
  bf16*  w2b = (bf16*)(ws + (64u<<20));
  bf16*  l1  = (bf16*)(ws + (66u<<20));
  float* z   = (float*)(ws + (74u<<20));

  const int NX  = BN*SEQ*DIM;
  const int NW1 = 4*DIM*DIM;
  const int NW2 = DIM*DIM;
  f2bk3<<<dim3((NX+NW1+NW2)/1024), dim3(256), 0, stream>>>(x, xb, NX, w1, w1b, NW1, w2, w2b);

  gemm_bt<4096><<<dim3(1024), dim3(256), 0, stream>>>(xb, w1b, b1, h, vt);
  attn<<<dim3(256), dim3(256), 0, stream>>>(h, vt, pw, y);
  lnorm<false,false><<<dim3(4096), dim3(256), 0, stream>>>(y, g1, be1, l1);
  gemm_bt2<<<dim3(512), dim3(256), 0, stream>>>(l1, w2b, b2, x, z);
  lnorm<true,true><<<dim3(4096), dim3(256), 0, stream>>>(z, g2, be2, d_out);
}

// Round 7
// 244.310 us; speedup vs baseline: 1.1118x; 1.1118x over previous
//
#include <hip/hip_runtime.h>
#include <hip/hip_bf16.h>

#define BN   2
#define SEQ  2048
#define DIM  1024
#define NH   16
#define HD   64
#define D4   4096
#define MAXS 4096

using bf16 = __hip_bfloat16;
typedef __bf16 bf16x8 __attribute__((ext_vector_type(8)));
typedef float  f32x4  __attribute__((ext_vector_type(4)));

__device__ __forceinline__ float bf2f(bf16 v){ return __bfloat162float(v); }
__device__ __forceinline__ bf16  f2bf(float v){ return __float2bfloat16(v); }
__device__ __forceinline__ float silu_f(float v){
  const float e = __expf(-v);
  return v * __builtin_amdgcn_rcpf(1.f + e);
}

__device__ __forceinline__ void async16(void* lds, const void* g){
  __builtin_amdgcn_global_load_lds((const __attribute__((address_space(1))) void*)g,
                                   (__attribute__((address_space(3))) void*)lds, 16, 0, 0);
}
__device__ __forceinline__ f32x4 mfma16(bf16x8 a, bf16x8 b, f32x4 c){
  return __builtin_amdgcn_mfma_f32_16x16x32_bf16(a, b, c, 0, 0, 0);
}

// ---------------- fp32 -> bf16 convert (3 arrays, 1 launch) ----------------
__global__ __launch_bounds__(256) void f2bk3(
    const float* __restrict__ a, bf16* __restrict__ ao, int na,
    const float* __restrict__ b, bf16* __restrict__ bo, int nb,
    const float* __restrict__ c, bf16* __restrict__ co)
{
  int i = (blockIdx.x * 256 + threadIdx.x) * 4;
  const float* in; bf16* out;
  if (i < na){ in = a; out = ao; }
  else if (i < na + nb){ in = b; out = bo; i -= na; }
  else { in = c; out = co; i -= na + nb; }
  const float4 v = *(const float4*)(in + i);
  bf16 t0 = f2bf(v.x), t1 = f2bf(v.y), t2 = f2bf(v.z), t3 = f2bf(v.w);
  ushort4 o;
  o.x = *(unsigned short*)&t0; o.y = *(unsigned short*)&t1;
  o.z = *(unsigned short*)&t2; o.w = *(unsigned short*)&t3;
  *(ushort4*)((unsigned short*)out + i) = o;
}

// ---------------- GEMM1: C = silu(A @ W^T + bias); v-tiles write transposed vt ----------------
template<int NTOT>
__global__ __launch_bounds__(256) void gemm_bt(
    const bf16* __restrict__ A, const bf16* __restrict__ W,
    const float* __restrict__ bias, bf16* __restrict__ outb, bf16* __restrict__ vt)
{
  constexpr int K = DIM;
  const int ntiles = NTOT / 128;
  const int m0 = (int)(blockIdx.x / ntiles) * 128;
  const int n0 = (int)(blockIdx.x % ntiles) * 128;
  __shared__ bf16 Al[128*32];
  __shared__ bf16 Bl[128*32];
  const int tid = threadIdx.x, wave = tid>>6, lane = tid&63;
  const int quad = lane>>4, l16 = lane&15;
  const int srow = lane>>2;
  const int sg   = ((lane&3) ^ ((lane>>3)&3)) * 8;
  const int wm = (wave>>1)*64, wn = (wave&1)*64;
  const int rkey = ((l16>>1)&3);

  f32x4 acc[4][4];
  #pragma unroll
  for (int i=0;i<4;i++)
    #pragma unroll
    for (int j=0;j<4;j++) acc[i][j] = (f32x4){0.f,0.f,0.f,0.f};

  const bf16* aB = A + m0*K;
  const bf16* wB = W + n0*K;

  for (int k0 = 0; k0 < K; k0 += 32){
    async16(&Al[wave*1024      ], aB + (wave*32      + srow)*K + k0 + sg);
    async16(&Al[wave*1024 + 512], aB + (wave*32 + 16 + srow)*K + k0 + sg);
    async16(&Bl[wave*1024      ], wB + (wave*32      + srow)*K + k0 + sg);
    async16(&Bl[wave*1024 + 512], wB + (wave*32 + 16 + srow)*K + k0 + sg);
    __syncthreads();
    bf16x8 af[4], bv[4];
    #pragma unroll
    for (int mt=0;mt<4;mt++) af[mt] = *(const bf16x8*)&Al[(wm+mt*16+l16)*32 + (quad ^ rkey)*8];
    #pragma unroll
    for (int nt=0;nt<4;nt++) bv[nt] = *(const bf16x8*)&Bl[(wn+nt*16+l16)*32 + (quad ^ rkey)*8];
    #pragma unroll
    for (int mt=0;mt<4;mt++)
      #pragma unroll
      for (int nt=0;nt<4;nt++)
        acc[mt][nt] = mfma16(af[mt], bv[nt], acc[mt][nt]);
    __syncthreads();
  }

  const bool vtile = (NTOT == 4096) && (n0 >= 3*DIM);
  if (!vtile){
    #pragma unroll
    for (int mt=0;mt<4;mt++){
      #pragma unroll
      for (int nt=0;nt<4;nt++){
        const int row = m0 + wm + mt*16 + quad*4;
        const int col = n0 + wn + nt*16 + l16;
        const float bvv = bias[col];
        #pragma unroll
        for (int r=0;r<4;r++){
          float v = silu_f(acc[mt][nt][r] + bvv);
          outb[(row+r)*NTOT + col] = f2bf(v);
        }
      }
    }
  } else {
    // v slice: write transposed directly to vt[b][hh][d][s] (4 consecutive s -> 8B store)
    #pragma unroll
    for (int mt=0;mt<4;mt++){
      #pragma unroll
      for (int nt=0;nt<4;nt++){
        const int row = m0 + wm + mt*16 + quad*4;
        const int colg = n0 + wn + nt*16 + l16;
        const float bvv = bias[colg];
        const int col = colg - 3*DIM;
        const int hh = col >> 6, d = col & 63;
        const int bb = row >> 11, sl = row & 2047;
        ushort4 o;
        float v0 = silu_f(acc[mt][nt][0] + bvv);
        float v1 = silu_f(acc[mt][nt][1] + bvv);
        float v2 = silu_f(acc[mt][nt][2] + bvv);
        float v3 = silu_f(acc[mt][nt][3] + bvv);
        bf16 t0=f2bf(v0), t1=f2bf(v1), t2=f2bf(v2), t3=f2bf(v3);
        o.x=*(unsigned short*)&t0; o.y=*(unsigned short*)&t1;
        o.z=*(unsigned short*)&t2; o.w=*(unsigned short*)&t3;
        *(ushort4*)&vt[((bb*NH + hh)*HD + d)*SEQ + sl] = o;
      }
    }
  }
}

// ---------------- GEMM2: z = A @ W^T + bias + resid, 128x64 tile, fp32 out ----------------
__global__ __launch_bounds__(256) void gemm_bt2(
    const bf16* __restrict__ A, const bf16* __restrict__ W,
    const float* __restrict__ bias, const float* __restrict__ resid,
    float* __restrict__ outf)
{
  constexpr int K = DIM, NTOT = DIM;
  const int ntiles = NTOT / 64;
  const int m0 = (int)(blockIdx.x / ntiles) * 128;
  const int n0 = (int)(blockIdx.x % ntiles) * 64;
  __shared__ bf16 Al[128*32];
  __shared__ bf16 Bl[64*32];
  const int tid = threadIdx.x, wave = tid>>6, lane = tid&63;
  const int quad = lane>>4, l16 = lane&15;
  const int srow = lane>>2;
  const int sg   = ((lane&3) ^ ((lane>>3)&3)) * 8;
  const int wm = wave*32;
  const int rkey = ((l16>>1)&3);

  f32x4 acc[2][4];
  #pragma unroll
  for (int i=0;i<2;i++)
    #pragma unroll
    for (int j=0;j<4;j++) acc[i][j] = (f32x4){0.f,0.f,0.f,0.f};

  const bf16* aB = A + m0*K;
  const bf16* wB = W + n0*K;

  for (int k0 = 0; k0 < K; k0 += 32){
    async16(&Al[wave*1024      ], aB + (wave*32      + srow)*K + k0 + sg);
    async16(&Al[wave*1024 + 512], aB + (wave*32 + 16 + srow)*K + k0 + sg);
    async16(&Bl[wave*512       ], wB + (wave*16      + srow)*K + k0 + sg);
    __syncthreads();
    bf16x8 af[2], bv[4];
    #pragma unroll
    for (int mt=0;mt<2;mt++) af[mt] = *(const bf16x8*)&Al[(wm+mt*16+l16)*32 + (quad ^ rkey)*8];
    #pragma unroll
    for (int nt=0;nt<4;nt++) bv[nt] = *(const bf16x8*)&Bl[(nt*16+l16)*32 + (quad ^ rkey)*8];
    #pragma unroll
    for (int mt=0;mt<2;mt++)
      #pragma unroll
      for (int nt=0;nt<4;nt++)
        acc[mt][nt] = mfma16(af[mt], bv[nt], acc[mt][nt]);
    __syncthreads();
  }

  #pragma unroll
  for (int mt=0;mt<2;mt++){
    #pragma unroll
    for (int nt=0;nt<4;nt++){
      const int row = m0 + wm + mt*16 + quad*4;
      const int col = n0 + nt*16 + l16;
      const float bvv = bias[col];
      #pragma unroll
      for (int r=0;r<4;r++){
        outf[(row+r)*NTOT + col] = acc[mt][nt][r] + bvv + resid[(row+r)*NTOT + col];
      }
    }
  }
}

// ---------------- attention (R5 skeleton + S^T trick) ----------------
// block = (b, head, q-tile PAIR {qp,31-qp}); grid 512 = 2 blocks/CU; bid%8 = XCD group.
// QK computed TRANSPOSED (S^T = K @ Q^T, just swapped mfma operands): lane's 4 acc
// elems = 4 consecutive kpos -> P spill is one ds_write_b64 instead of 4 ds_write_b16.
__global__ __launch_bounds__(256) void attn(
    const bf16* __restrict__ h, const bf16* __restrict__ vt,
    const float* __restrict__ pw, bf16* __restrict__ y)
{
  const int bid = blockIdx.x;
  const int g  = (bid & 7) + ((bid >> 7) << 3);   // (b,head) group 0..31
  const int qp = (bid >> 3) & 15;
  const int hh = g & 15, b = g >> 4;
  __shared__ bf16 Kl[128*64];     // [kpos][d], groups xor-swizzled by kpos&7
  __shared__ bf16 Vl[64*128];     // [d][kpos], groups xor-swizzled by d&15
  __shared__ bf16 Pl[4][16*136];  // per-wave P [qrow][kpos], stride 136
  __shared__ float pwl[256];
  const int tid = threadIdx.x, wave = tid>>6, lane = tid&63;
  const int quad = lane>>4, l16 = lane&15;

  const bf16* kgb = h + b*SEQ*D4 + 2*DIM + hh*HD;
  const bf16* vgb = vt + (b*NH + hh)*HD*SEQ;
  const int krow8 = lane>>3;
  const int kgo   = ((lane&7) ^ krow8) * 8;
  const int vrow4 = lane>>4;

  #pragma unroll
  for (int pass = 0; pass < 2; ++pass){
    const int qt = pass ? (31 - qp) : qp;
    const int q0 = qt * 64;

    const bf16* qbase = h + (b*SEQ + q0 + wave*16 + l16)*D4 + DIM + hh*HD;
    bf16x8 qf[2];
    qf[0] = *(const bf16x8*)(qbase + quad*8);
    qf[1] = *(const bf16x8*)(qbase + 32 + quad*8);

    f32x4 oacc[4];
    #pragma unroll
    for (int nt=0;nt<4;nt++) oacc[nt] = (f32x4){0.f,0.f,0.f,0.f};

    const int kmax = q0 + 64;
    for (int k0 = 0; k0 < kmax; k0 += 128){
      #pragma unroll
      for (int t=0;t<4;t++)
        async16(&Kl[(wave*32 + t*8)*64], kgb + (k0 + wave*32 + t*8 + krow8)*D4 + kgo);
      #pragma unroll
      for (int t=0;t<4;t++){
        const int vg = ((lane&15) ^ (t*4 + vrow4)) * 8;
        async16(&Vl[(wave*16 + t*4)*128], vgb + (wave*16 + t*4 + vrow4)*SEQ + k0 + vg);
      }
      const int W0 = MAXS - 1 + k0 - q0 - 63;
      if (wave == 0) async16(&pwl[0], pw + W0 + lane*4);
      __syncthreads();

      // S^T = K @ Q^T  (m=128 kpos as 8 nt-frags, n=16 qrows, k=64)
      f32x4 sacc[8];
      #pragma unroll
      for (int nt=0;nt<8;nt++) sacc[nt] = (f32x4){0.f,0.f,0.f,0.f};
      #pragma unroll
      for (int ks=0;ks<2;ks++){
        #pragma unroll
        for (int nt=0;nt<8;nt++){
          bf16x8 kf = *(const bf16x8*)&Kl[(nt*16 + l16)*64 + ((ks*4 + quad) ^ (l16&7))*8];
          sacc[nt] = mfma16(kf, qf[ks], sacc[nt]);   // A=K, B=Q^T  -> C = S^T
        }
      }

      // bias + silu + causal; lane holds 4 consecutive kpos for fixed qrow=l16
      const int dq = q0 - k0;
      const int qrl = wave*16 + l16;          // qrow_local in 64-tile... (wave row block)
      #pragma unroll
      for (int nt=0;nt<8;nt++){
        const int kb = nt*16 + quad*4;        // kpos_local base
        const int d0 = kb - qrl;              // d for r=0 (minus wave*16 folded below)
        ushort4 o;
        bf16 tb[4];
        #pragma unroll
        for (int r=0;r<4;r++){
          const int d = kb + r - qrl;
          const float bias = pwl[d + 63];
          const float sv = silu_f(sacc[nt][r] + bias);
          tb[r] = f2bf((d <= dq) ? sv : 0.f);
        }
        (void)d0;
        o.x=*(unsigned short*)&tb[0]; o.y=*(unsigned short*)&tb[1];
        o.z=*(unsigned short*)&tb[2]; o.w=*(unsigned short*)&tb[3];
        *(ushort4*)&Pl[wave][l16*136 + kb] = o;
      }

      // O += P @ V  (m=16 qrows, n=64 d, k=128 kpos)
      #pragma unroll
      for (int ks=0;ks<4;ks++){
        bf16x8 pf = *(const bf16x8*)&Pl[wave][l16*136 + ks*32 + quad*8];
        #pragma unroll
        for (int nt=0;nt<4;nt++){
          bf16x8 vf = *(const bf16x8*)&Vl[(nt*16 + l16)*128 + ((ks*4 + quad) ^ l16)*8];
          oacc[nt] = mfma16(pf, vf, oacc[nt]);
        }
      }
      __syncthreads();   // protect Kl/Vl/pwl before restage
    }

    // epilogue: multiply by u, write y
    const int qrow = q0 + wave*16 + quad*4;
    #pragma unroll
    for (int nt=0;nt<4;nt++){
      const int c = hh*HD + nt*16 + l16;
      #pragma unroll
      for (int r=0;r<4;r++){
        const int srow = b*SEQ + qrow + r;
        const float uu = bf2f(h[srow*D4 + c]);
        y[srow*DIM + c] = f2bf(oacc[nt][r] * uu);
      }
    }
    __syncthreads();
  }
}

// NOTE on pwl indexing above: d = (kb + r) - (wave*16 + l16) and the staged window
// W0 = MAXS-1+k0-q0-63 gives pwl[d + 63] with d in [-63, 127] -> idx in [0,190]. qrl
// includes wave*16, matching the window's q0-relative origin.

// ---------------- row layernorm over D=1024 ----------------
template<bool FP32IN, bool FP32OUT>
__global__ __launch_bounds__(256) void lnorm(const void* __restrict__ in,
    const float* __restrict__ g, const float* __restrict__ be, void* __restrict__ out)
{
  const int row = blockIdx.x;
  const int tid = threadIdx.x, wave = tid>>6, lane = tid&63;
  const int c0 = tid*4;
  float v[4];
  if (FP32IN){
    const float* p = (const float*)in + row*DIM + c0;
    #pragma unroll
    for (int j=0;j<4;j++) v[j] = p[j];
  } else {
    const bf16* p = (const bf16*)in + row*DIM + c0;
    #pragma unroll
    for (int j=0;j<4;j++) v[j] = bf2f(p[j]);
  }
  float s = 0.f, ss = 0.f;
  #pragma unroll
  for (int j=0;j<4;j++){ s += v[j]; ss += v[j]*v[j]; }
  #pragma unroll
  for (int off=32; off>0; off>>=1){
    s  += __shfl_down(s, off);
    ss += __shfl_down(ss, off);
  }
  __shared__ float red[8];
  if (lane==0){ red[wave] = s; red[4+wave] = ss; }
  __syncthreads();
  s  = red[0]+red[1]+red[2]+red[3];
  ss = red[4]+red[5]+red[6]+red[7];
  const float mu   = s * (1.f/DIM);
  const float var  = ss * (1.f/DIM) - mu*mu;
  const float rstd = rsqrtf(var + 1e-5f);
  #pragma unroll
  for (int j=0;j<4;j++){
    const int c = c0 + j;
    const float o = (v[j]-mu)*rstd*g[c] + be[c];
    if (FP32OUT) ((float*)out)[row*DIM + c] = o;
    else         ((bf16*)out)[row*DIM + c] = f2bf(o);
  }
}

extern "C" void kernel_launch(void* const* d_in, const int* in_sizes, int n_in,
                              void* d_out, int out_size, void* d_ws, size_t ws_size,
                              hipStream_t stream)
{
  const float* x   = (const float*)d_in[0];
  const float* w1  = (const float*)d_in[2];
  const float* b1  = (const float*)d_in[3];
  const float* w2  = (const float*)d_in[4];
  const float* b2  = (const float*)d_in[5];
  const float* g1  = (const float*)d_in[6];
  const float* be1 = (const float*)d_in[7];
  const float* g2  = (const float*)d_in[8];
  const float* be2 = (const float*)d_in[9];
  const float* pw  = (const float*)d_in[10];

  char* ws = (char*)d_ws;
  bf16*  h   = (bf16*)(ws);
  bf16*  vt  = (bf16*)(ws + (32u<<20));
  bf16*  y   = (bf16*)(ws + (40u<<20));
  bf16*  xb  = (bf16*)(ws + (48u<<20));
  bf16*  w1b = (bf16*)(ws + (56u<<20));
  bf16*  w2b = (bf16*)(ws + (64u<<20));
  bf16*  l1  = (bf16*)(ws + (66u<<20));
  float* z   = (float*)(ws + (74u<<20));

  const int NX  = BN*SEQ*DIM;
  const int NW1 = 4*DIM*DIM;
  const int NW2 = DIM*DIM;
  f2bk3<<<dim3((NX+NW1+NW2)/1024), dim3(256), 0, stream>>>(x, xb, NX, w1, w1b, NW1, w2, w2b);

  gemm_bt<4096><<<dim3(1024), dim3(256), 0, stream>>>(xb, w1b, b1, h, vt);
  attn<<<dim3(512), dim3(256), 0, stream>>>(h, vt, pw, y);
  lnorm<false,false><<<dim3(4096), dim3(256), 0, stream>>>(y, g1, be1, l1);
  gemm_bt2<<<dim3(512), dim3(256), 0, stream>>>(l1, w2b, b2, x, z);
  lnorm<true,true><<<dim3(4096), dim3(256), 0, stream>>>(z, g2, be2, d_out);
}